// Round 1
// baseline (857.516 us; speedup 1.0000x reference)
//
#include <hip/hip_runtime.h>

// DynamicFilterLayerOneChannel: out[n,h,w] = sum_{ky,kx} x[n,h+ky-4,w+kx-4]*F[n,ky*9+kx,h,w] + b[n,h,w]
// Memory-bound on streaming F (~677 MB). Each thread computes 4 consecutive
// w-pixels so every filter read is a coalesced float4 (16B/lane).

#define KS   9
#define PADV 4
#define NN   4
#define HH   544
#define WW   960
#define W4   (WW / 4)

__global__ __launch_bounds__(256) void dynfilter_kernel(
    const float* __restrict__ x,
    const float* __restrict__ filt,
    const float* __restrict__ bias,
    float* __restrict__ out)
{
    int idx = blockIdx.x * blockDim.x + threadIdx.x;
    const int total = NN * HH * W4;
    if (idx >= total) return;

    int w4 = idx % W4;
    int t  = idx / W4;
    int h  = t % HH;
    int n  = t / HH;
    int w0 = w4 * 4;

    const size_t hw = (size_t)HH * WW;
    const float* __restrict__ xb = x + (size_t)n * hw;
    const float* __restrict__ fb = filt + (size_t)n * (size_t)(KS * KS) * hw
                                        + (size_t)h * WW + w0;
    const size_t oi = (size_t)n * hw + (size_t)h * WW + w0;

    float4 acc = *reinterpret_cast<const float4*>(bias + oi);

    const bool interior = (w0 >= PADV) && (w0 + 7 < WW) &&
                          (h >= PADV) && (h + PADV < HH);

    if (interior) {
        // fast path: aligned float4 x-row loads, no bounds checks
        #pragma unroll
        for (int dy = 0; dy < KS; ++dy) {
            const float* xr = xb + (size_t)(h + dy - PADV) * WW + (w0 - PADV);
            float4 a = *reinterpret_cast<const float4*>(xr);
            float4 b = *reinterpret_cast<const float4*>(xr + 4);
            float4 c = *reinterpret_cast<const float4*>(xr + 8);
            float xrow[12] = {a.x, a.y, a.z, a.w,
                              b.x, b.y, b.z, b.w,
                              c.x, c.y, c.z, c.w};
            #pragma unroll
            for (int dx = 0; dx < KS; ++dx) {
                float4 f = *reinterpret_cast<const float4*>(
                    fb + (size_t)(dy * KS + dx) * hw);
                acc.x += f.x * xrow[dx + 0];
                acc.y += f.y * xrow[dx + 1];
                acc.z += f.z * xrow[dx + 2];
                acc.w += f.w * xrow[dx + 3];
            }
        }
    } else {
        // boundary path: predicated scalar x loads (zero padding)
        #pragma unroll
        for (int dy = 0; dy < KS; ++dy) {
            int row = h + dy - PADV;
            float xrow[12];
            #pragma unroll
            for (int j = 0; j < 12; ++j) {
                int col = w0 - PADV + j;
                bool ok = (row >= 0) && (row < HH) && (col >= 0) && (col < WW);
                xrow[j] = ok ? xb[(size_t)row * WW + col] : 0.0f;
            }
            #pragma unroll
            for (int dx = 0; dx < KS; ++dx) {
                float4 f = *reinterpret_cast<const float4*>(
                    fb + (size_t)(dy * KS + dx) * hw);
                acc.x += f.x * xrow[dx + 0];
                acc.y += f.y * xrow[dx + 1];
                acc.z += f.z * xrow[dx + 2];
                acc.w += f.w * xrow[dx + 3];
            }
        }
    }

    *reinterpret_cast<float4*>(out + oi) = acc;
}

extern "C" void kernel_launch(void* const* d_in, const int* in_sizes, int n_in,
                              void* d_out, int out_size, void* d_ws, size_t ws_size,
                              hipStream_t stream) {
    const float* x    = (const float*)d_in[0];  // [4,1,544,960]
    const float* filt = (const float*)d_in[1];  // [4,81,544,960]
    const float* bias = (const float*)d_in[2];  // [4,1,544,960]
    float* out        = (float*)d_out;          // [4,1,544,960]

    const int total  = NN * HH * W4;            // 522240 threads
    const int block  = 256;
    const int grid   = (total + block - 1) / block;
    dynfilter_kernel<<<grid, block, 0, stream>>>(x, filt, bias, out);
}

// Round 3
// 851.057 us; speedup vs baseline: 1.0076x; 1.0076x over previous
//
#include <hip/hip_runtime.h>

// DynamicFilterLayerOneChannel:
//   out[n,h,w] = sum_{ky,kx} x[n,h+ky-4,w+kx-4] * F[n,ky*9+kx,h,w] + b[n,h,w]
// Memory-bound on streaming F (~677 MB, read once). Each thread computes 4
// consecutive w-pixels so every filter read is a coalesced float4 (16B/lane).
// dy-loop kept rolled (#pragma unroll 1) to cap VGPR pressure -> no spills;
// launch_bounds(256,4) caps VGPRs at 128 (4 waves/EU).

#define KS   9
#define PADV 4
#define NN   4
#define HH   544
#define WW   960
#define W4   (WW / 4)          // 240
#define HW   (HH * WW)         // 522240

typedef float vf4 __attribute__((ext_vector_type(4)));  // native vector for nt builtins

__global__ __launch_bounds__(256, 4) void dynfilter_kernel(
    const float* __restrict__ x,
    const float* __restrict__ filt,
    const float* __restrict__ bias,
    float* __restrict__ out)
{
    const int n = blockIdx.y;                       // wave-uniform batch
    const int p = blockIdx.x * 256 + threadIdx.x;   // pixel-group id, < 130560
    const int w4 = p % W4;
    const int h  = p / W4;
    const int w0 = w4 * 4;

    const float* __restrict__ xb = x + (size_t)n * HW;
    const float* __restrict__ fn = filt + (size_t)n * KS * KS * HW;  // scalar base
    const int off = h * WW + w0;                    // per-lane 32-bit offset

    vf4 acc = *reinterpret_cast<const vf4*>(bias + (size_t)n * HW + off);

    const bool interior = (w0 >= PADV) && (w0 + 7 < WW) &&
                          (h >= PADV) && (h + PADV < HH);

    if (interior) {
        const float* xr = xb + (h - PADV) * WW + (w0 - PADV);
        const float* fp = fn + off;
        #pragma unroll 1
        for (int dy = 0; dy < KS; ++dy) {
            vf4 a = *reinterpret_cast<const vf4*>(xr);
            vf4 b = *reinterpret_cast<const vf4*>(xr + 4);
            vf4 c = *reinterpret_cast<const vf4*>(xr + 8);
            float xrow[12] = {a.x, a.y, a.z, a.w,
                              b.x, b.y, b.z, b.w,
                              c.x, c.y, c.z, c.w};
            #pragma unroll
            for (int dx = 0; dx < KS; ++dx) {
                vf4 f = __builtin_nontemporal_load(
                    reinterpret_cast<const vf4*>(fp + (size_t)dx * HW));
                acc.x += f.x * xrow[dx + 0];
                acc.y += f.y * xrow[dx + 1];
                acc.z += f.z * xrow[dx + 2];
                acc.w += f.w * xrow[dx + 3];
            }
            xr += WW;
            fp += (size_t)KS * HW;
        }
    } else {
        const float* fp = fn + off;
        #pragma unroll 1
        for (int dy = 0; dy < KS; ++dy) {
            int row = h + dy - PADV;
            bool rok = (row >= 0) && (row < HH);
            float xrow[12];
            #pragma unroll
            for (int j = 0; j < 12; ++j) {
                int col = w0 - PADV + j;
                bool ok = rok && (col >= 0) && (col < WW);
                xrow[j] = ok ? xb[row * WW + col] : 0.0f;
            }
            #pragma unroll
            for (int dx = 0; dx < KS; ++dx) {
                vf4 f = __builtin_nontemporal_load(
                    reinterpret_cast<const vf4*>(fp + (size_t)dx * HW));
                acc.x += f.x * xrow[dx + 0];
                acc.y += f.y * xrow[dx + 1];
                acc.z += f.z * xrow[dx + 2];
                acc.w += f.w * xrow[dx + 3];
            }
            fp += (size_t)KS * HW;
        }
    }

    __builtin_nontemporal_store(acc,
        reinterpret_cast<vf4*>(out + (size_t)n * HW + off));
}

extern "C" void kernel_launch(void* const* d_in, const int* in_sizes, int n_in,
                              void* d_out, int out_size, void* d_ws, size_t ws_size,
                              hipStream_t stream) {
    const float* x    = (const float*)d_in[0];  // [4,1,544,960]
    const float* filt = (const float*)d_in[1];  // [4,81,544,960]
    const float* bias = (const float*)d_in[2];  // [4,1,544,960]
    float* out        = (float*)d_out;          // [4,1,544,960]

    dim3 grid((HH * W4) / 256, NN);             // 510 x 4 blocks, exact cover
    dynfilter_kernel<<<grid, dim3(256), 0, stream>>>(x, filt, bias, out);
}